// Round 1
// baseline (394.299 us; speedup 1.0000x reference)
//
#include <hip/hip_runtime.h>

#define ZDIM 4096
#define DIN  256
#define DTS  2048
#define DOUT 256
#define CDIM 65536
#define SPLIT 8
#define CHUNK (CDIM / SPLIT)

typedef float fv4 __attribute__((ext_vector_type(4)));
typedef __bf16 bv8 __attribute__((ext_vector_type(8)));
typedef unsigned short u16;
typedef u16 uv8 __attribute__((ext_vector_type(8)));
typedef u16 uv4 __attribute__((ext_vector_type(4)));

union BC  { __bf16 b; u16 u; };
union VC8 { uv8 u; bv8 b; };

static __device__ __forceinline__ u16  f2b(float f){ BC c; c.b=(__bf16)f; return c.u; }
static __device__ __forceinline__ float b2f(u16 v){ BC c; c.u=v; return (float)c.b; }
static __device__ __forceinline__ bv8  asb(uv8 x){ VC8 c; c.u=x; return c.b; }
static __device__ __forceinline__ uv8  pack8(fv4 a, fv4 b){
  uv8 p;
  p[0]=f2b(a[0]); p[1]=f2b(a[1]); p[2]=f2b(a[2]); p[3]=f2b(a[3]);
  p[4]=f2b(b[0]); p[5]=f2b(b[1]); p[6]=f2b(b[2]); p[7]=f2b(b[3]);
  return p;
}

// ---------------------------------------------------------------------------
// Kernel 1: Kmat[k][c] = sum_t W[k][t] * T[t][c]   (bf16 output in ws)
// grid 512 c-blocks of 128, block 512 = 8 waves (4 k-tiles x 2 c-tiles of 64)
// ---------------------------------------------------------------------------
__global__ __launch_bounds__(512, 2) void k_wt(const float* __restrict__ W,
                                               const float* __restrict__ T,
                                               u16* __restrict__ Km) {
  __shared__ u16 Al[256 * 40];   // W tile [k][t], padded stride 40
  __shared__ u16 Bl[32 * 128];   // T tile [t][c], row-major
  const int tid  = threadIdx.x;
  const int lane = tid & 63;
  const int wave = tid >> 6;
  const int wk = (wave >> 1) * 64;
  const int wc = (wave & 1) * 64;
  const int cb = blockIdx.x * 128;
  const int ar = lane & 15, tg = lane >> 4;

  fv4 acc[4][4];
#pragma unroll
  for (int m = 0; m < 4; ++m)
#pragma unroll
    for (int n = 0; n < 4; ++n)
#pragma unroll
      for (int r = 0; r < 4; ++r) acc[m][n][r] = 0.f;

  for (int t0 = 0; t0 < DTS; t0 += 32) {
    // stage W tile: 256 rows x 32 t (bf16)
#pragma unroll
    for (int p = 0; p < 2; ++p) {
      int oct = tid + p * 512;
      int kr = oct >> 2, ts = (oct & 3) * 8;
      const float* src = W + (size_t)kr * DTS + t0 + ts;
      fv4 a = *(const fv4*)src, b = *(const fv4*)(src + 4);
      *(uv8*)&Al[kr * 40 + ts] = pack8(a, b);
    }
    // stage T tile: 32 rows x 128 c, row-major (coalesced)
    {
      int tr = tid >> 4, co = (tid & 15) * 8;
      const float* src = T + (size_t)(t0 + tr) * CDIM + cb + co;
      fv4 a = *(const fv4*)src, b = *(const fv4*)(src + 4);
      *(uv8*)&Bl[tr * 128 + co] = pack8(a, b);
    }
    __syncthreads();
    bv8 af[4];
#pragma unroll
    for (int m = 0; m < 4; ++m)
      af[m] = asb(*(const uv8*)&Al[(wk + m * 16 + ar) * 40 + tg * 8]);
#pragma unroll
    for (int n = 0; n < 4; ++n) {
      uv8 bu;
#pragma unroll
      for (int e = 0; e < 8; ++e)
        bu[e] = Bl[(tg * 8 + e) * 128 + wc + n * 16 + ar];
      bv8 bf = asb(bu);
#pragma unroll
      for (int m = 0; m < 4; ++m)
        acc[m][n] = __builtin_amdgcn_mfma_f32_16x16x32_bf16(af[m], bf, acc[m][n], 0, 0, 0);
    }
    __syncthreads();
  }
  // epilogue: D row=(lane>>4)*4+r (k), col=lane&15 (c)
#pragma unroll
  for (int m = 0; m < 4; ++m)
#pragma unroll
    for (int n = 0; n < 4; ++n)
#pragma unroll
      for (int r = 0; r < 4; ++r) {
        int kr = wk + m * 16 + tg * 4 + r;
        int cc = cb + wc + n * 16 + ar;
        Km[(size_t)kr * CDIM + cc] = f2b(acc[m][n][r]);
      }
}

// ---------------------------------------------------------------------------
// Kernel 2: partial[s][z][k] = sum_{c in chunk s} O[z,c]*Kmat[k,c]
//           O[z,c] = x[z, c>>8] * x[z, c&255]  (built on the fly in LDS)
// grid 512 linear (bid&7 = split chunk -> XCD-affine, bid>>3 = z-panel of 64)
// block 512 = 8 waves, each wave owns a 64(z) x 32(k) output slice
// ---------------------------------------------------------------------------
__global__ __launch_bounds__(512, 4) void k_bil(const float* __restrict__ X,
                                                const u16* __restrict__ Km,
                                                float* __restrict__ P) {
  __shared__ u16 Xl[64 * 264];   // x tile bf16, padded stride 264
  __shared__ u16 Ol[64 * 40];    // O tile [z][32 c], padded stride 40
  __shared__ u16 Bl[256 * 40];   // Kmat tile [k][32 c], padded stride 40
  const int tid  = threadIdx.x;
  const int lane = tid & 63;
  const int wave = tid >> 6;
  const int wkk  = wave * 32;
  const int bid  = blockIdx.x;
  const int s    = bid & 7;        // split-K chunk (XCD-affine under RR dispatch)
  const int z0   = (bid >> 3) * 64;
  const int cs   = s * CHUNK;
  const int ar = lane & 15, tg = lane >> 4;

  // stage X rows z0..z0+63 as bf16
  for (int idx = tid; idx < 64 * 32; idx += 512) {
    int row = idx >> 5, sg = (idx & 31) * 8;
    const float* src = X + (size_t)(z0 + row) * DIN + sg;
    fv4 a = *(const fv4*)src, b = *(const fv4*)(src + 4);
    *(uv8*)&Xl[row * 264 + sg] = pack8(a, b);
  }
  __syncthreads();

  fv4 acc[4][2];
#pragma unroll
  for (int m = 0; m < 4; ++m)
#pragma unroll
    for (int n = 0; n < 2; ++n)
#pragma unroll
      for (int r = 0; r < 4; ++r) acc[m][n][r] = 0.f;

  const int zr  = tid & 63;            // O-build: my z row
  const int oc  = (tid >> 6) * 4;      // O-build: my 4-wide c slot
  const int kks = tid >> 2;            // B-stage: my k row (+128 on 2nd pass)
  const int qq  = (tid & 3) * 8;       // B-stage: my 8-wide c slot

  for (int cc = 0; cc < CHUNK; cc += 32) {
    int cg = cs + cc;
    int i  = cg >> 8, j0 = cg & 255;   // c = i*256 + j; i constant over 32-span
    // build O tile: O[z][0..31] = x[z][i] * x[z][j0..j0+31]
    {
      float xi = b2f(Xl[zr * 264 + i]);
      uv4 xj = *(const uv4*)&Xl[zr * 264 + j0 + oc];
      uv4 o;
#pragma unroll
      for (int e = 0; e < 4; ++e) o[e] = f2b(xi * b2f(xj[e]));
      *(uv4*)&Ol[zr * 40 + oc] = o;
    }
    // stage Kmat tile: [256 k][32 c]
#pragma unroll
    for (int p = 0; p < 2; ++p) {
      int kk = kks + p * 128;
      uv8 v = *(const uv8*)&Km[(size_t)kk * CDIM + cg + qq];
      *(uv8*)&Bl[kk * 40 + qq] = v;
    }
    __syncthreads();
    bv8 af[4], bf[2];
#pragma unroll
    for (int m = 0; m < 4; ++m)
      af[m] = asb(*(const uv8*)&Ol[(m * 16 + ar) * 40 + tg * 8]);
#pragma unroll
    for (int n = 0; n < 2; ++n)
      bf[n] = asb(*(const uv8*)&Bl[(wkk + n * 16 + ar) * 40 + tg * 8]);
#pragma unroll
    for (int n = 0; n < 2; ++n)
#pragma unroll
      for (int m = 0; m < 4; ++m)
        acc[m][n] = __builtin_amdgcn_mfma_f32_16x16x32_bf16(af[m], bf[n], acc[m][n], 0, 0, 0);
    __syncthreads();
  }
  float* dst = P + (size_t)s * (ZDIM * DOUT) + (size_t)z0 * DOUT;
#pragma unroll
  for (int m = 0; m < 4; ++m)
#pragma unroll
    for (int n = 0; n < 2; ++n)
#pragma unroll
      for (int r = 0; r < 4; ++r)
        dst[(size_t)(m * 16 + tg * 4 + r) * DOUT + wkk + n * 16 + ar] = acc[m][n][r];
}

// ---------------------------------------------------------------------------
// Kernel 3: out[z][k] = sum_s partial[s][z][k]
// ---------------------------------------------------------------------------
__global__ __launch_bounds__(256) void k_red(const float* __restrict__ P,
                                             float* __restrict__ O) {
  size_t idx = ((size_t)blockIdx.x * 256 + threadIdx.x) * 4;
  fv4 acc;
#pragma unroll
  for (int r = 0; r < 4; ++r) acc[r] = 0.f;
#pragma unroll
  for (int p = 0; p < SPLIT; ++p)
    acc += *(const fv4*)&P[(size_t)p * (ZDIM * DOUT) + idx];
  *(fv4*)&O[idx] = acc;
}

extern "C" void kernel_launch(void* const* d_in, const int* in_sizes, int n_in,
                              void* d_out, int out_size, void* d_ws, size_t ws_size,
                              hipStream_t stream) {
  const float* feat = (const float*)d_in[0];   // [4096, 256]
  const float* T    = (const float*)d_in[1];   // [2048, 65536]
  const float* W    = (const float*)d_in[2];   // [256, 2048]
  float* out = (float*)d_out;                  // [4096, 256]

  u16*   Km = (u16*)d_ws;                                        // 32 MB bf16 Kmat
  float* P  = (float*)((char*)d_ws + (size_t)DOUT * CDIM * 2);   // 32 MB partials

  k_wt <<<dim3(512),  dim3(512), 0, stream>>>(W, T, Km);
  k_bil<<<dim3(512),  dim3(512), 0, stream>>>(feat, Km, P);
  k_red<<<dim3(1024), dim3(256), 0, stream>>>(P, out);
}